// Round 6
// baseline (27.058 us; speedup 1.0000x reference)
//
#include <hip/hip_runtime.h>

#define NN     1024
#define IN_D   256
#define OUT_D  256
#define BN     4               // n-rows per block; grid = 256 = 1 block/CU
#define NI2    (IN_D / 2)      // 128 ii-pairs
#define NG     8               // K-groups (tid>>7), 32 i's each
#define JPG    (NI2 / NG)      // 16 ii-pairs per group
#define OSLOTS (OUT_D / 2)     // 128; thread owns o = oslot and oslot+128

typedef float v2f __attribute__((ext_vector_type(2)));
typedef float v4f __attribute__((ext_vector_type(4)));

__device__ __forceinline__ v2f wlr_of(const float* __restrict__ wb,
                                      const float* __restrict__ wa,
                                      const float* __restrict__ wc, int idx) {
    float b = wb[idx];
    v2f w;
    w.x = b - fmaxf(wa[idx], 0.0f);   // w_l
    w.y = b + fmaxf(wc[idx], 0.0f);   // w_r
    return w;
}

__global__ __launch_bounds__(1024) void fz_fused(
    const float* __restrict__ hl, const float* __restrict__ hr,
    const float* __restrict__ wb, const float* __restrict__ wa,
    const float* __restrict__ wc,
    const float* __restrict__ bb, const float* __restrict__ ba,
    const float* __restrict__ bc, float* __restrict__ out) {
    __shared__ __align__(16) v2f ab[BN][IN_D];            // 8 KB {hl,hr}
    __shared__ __align__(16) v2f pl[NG][BN][2][OSLOTS];   // 64 KB partials

    const int tid   = threadIdx.x;
    const int oslot = tid & (OSLOTS - 1);          // o0 = oslot, o1 = oslot+128
    const int g     = tid >> 7;                    // K-group 0..7
    const int n0    = blockIdx.x * BN;

    // stage BN rows of {hl,hr}: exactly one (row, ii) per thread, coalesced
    {
        int row = tid >> 8;
        int ii  = tid & (IN_D - 1);
        v2f v; v.x = hl[(n0 + row) * IN_D + ii];
        v.y = hr[(n0 + row) * IN_D + ii];
        ab[row][ii] = v;
    }
    __syncthreads();

    v2f acc[BN][2];
#pragma unroll
    for (int t = 0; t < BN; ++t) {
        acc[t][0].x = 0.0f; acc[t][0].y = 0.0f;
        acc[t][1].x = 0.0f; acc[t][1].y = 0.0f;
    }

    const int j0 = g * JPG;

#pragma unroll 4
    for (int j = 0; j < JPG; ++j) {
        // raw-W recompute: cells (i_a|i_b) x (o0|o1), i_a = (j0+j)*2
        const int base = (j0 + j) * 2 * OUT_D + oslot;   // (i_a, o0)
        v2f w00 = wlr_of(wb, wa, wc, base);                  // i_a, o0
        v2f w01 = wlr_of(wb, wa, wc, base + OSLOTS);         // i_a, o1
        v2f w10 = wlr_of(wb, wa, wc, base + OUT_D);          // i_b, o0
        v2f w11 = wlr_of(wb, wa, wc, base + OUT_D + OSLOTS); // i_b, o1

        const int ii = (j0 + j) * 2;
#pragma unroll
        for (int t = 0; t < BN; ++t) {
            v4f a4 = *reinterpret_cast<const v4f*>(&ab[t][ii]);  // broadcast b128
            v2f p0; p0.x = a4.x; p0.y = a4.y;      // {a,b} at i_a
            v2f p1; p1.x = a4.z; p1.y = a4.w;      // {a,b} at i_b
            // invariants: b>=a, wr>0 => min=min3(awl,bwl,awr), max=max3(awl,bwl,bwr)
            {   v2f l = p0 * w00.x, r = p0 * w00.y;            // o0, i_a
                v2f mm; mm.x = fminf(fminf(l.x, l.y), r.x);
                mm.y = fmaxf(fmaxf(l.x, l.y), r.y);
                acc[t][0] += mm; }
            {   v2f l = p1 * w10.x, r = p1 * w10.y;            // o0, i_b
                v2f mm; mm.x = fminf(fminf(l.x, l.y), r.x);
                mm.y = fmaxf(fmaxf(l.x, l.y), r.y);
                acc[t][0] += mm; }
            {   v2f l = p0 * w01.x, r = p0 * w01.y;            // o1, i_a
                v2f mm; mm.x = fminf(fminf(l.x, l.y), r.x);
                mm.y = fmaxf(fmaxf(l.x, l.y), r.y);
                acc[t][1] += mm; }
            {   v2f l = p1 * w11.x, r = p1 * w11.y;            // o1, i_b
                v2f mm; mm.x = fminf(fminf(l.x, l.y), r.x);
                mm.y = fmaxf(fmaxf(l.x, l.y), r.y);
                acc[t][1] += mm; }
        }
    }

    // all groups write partials (8B stride: 2-way aliasing = free)
#pragma unroll
    for (int t = 0; t < BN; ++t) {
        pl[g][t][0][oslot] = acc[t][0];
        pl[g][t][1][oslot] = acc[t][1];
    }
    __syncthreads();

    // groups 0..3 each combine one row; groups 4..7 done
    if (g < BN) {
        const int row = g;
        const int o0 = oslot, o1 = oslot + OSLOTS;
        v2f s0; s0.x = 0.0f; s0.y = 0.0f;
        v2f s1; s1.x = 0.0f; s1.y = 0.0f;
#pragma unroll
        for (int gg = 0; gg < NG; ++gg) {
            s0 += pl[gg][row][0][oslot];
            s1 += pl[gg][row][1][oslot];
        }
        float bl0 = bb[o0] - fmaxf(ba[o0], 0.0f);
        float br0 = bb[o0] + fmaxf(bc[o0], 0.0f);
        float bl1 = bb[o1] - fmaxf(ba[o1], 0.0f);
        float br1 = bb[o1] + fmaxf(bc[o1], 0.0f);
        size_t rl = (size_t)(n0 + row) * OUT_D;
        size_t rr = (size_t)NN * OUT_D + rl;
        out[rl + o0] = s0.x + bl0;
        out[rr + o0] = s0.y + br0;
        out[rl + o1] = s1.x + bl1;
        out[rr + o1] = s1.y + br1;
    }
}

extern "C" void kernel_launch(void* const* d_in, const int* in_sizes, int n_in,
                              void* d_out, int out_size, void* d_ws, size_t ws_size,
                              hipStream_t stream) {
    const float* hl = (const float*)d_in[0];
    const float* hr = (const float*)d_in[1];
    const float* wb = (const float*)d_in[2];
    const float* wa = (const float*)d_in[3];
    const float* wc = (const float*)d_in[4];
    const float* bb = (const float*)d_in[5];
    const float* ba = (const float*)d_in[6];
    const float* bc = (const float*)d_in[7];
    float* out = (float*)d_out;

    fz_fused<<<dim3(NN / BN), 1024, 0, stream>>>(hl, hr, wb, wa, wc,
                                                 bb, ba, bc, out);
}

// Round 7
// 24.034 us; speedup vs baseline: 1.1258x; 1.1258x over previous
//
#include <hip/hip_runtime.h>

#define NN     1024
#define IN_D   256
#define OUT_D  256
#define BN     4               // n-rows per block; grid = 256 = 1 block/CU
#define NI2    (IN_D / 2)      // 128 ii-pairs
#define NG     8               // K-groups (tid>>7), 32 i's each
#define JPG    (NI2 / NG)      // 16 ii-pairs per group
#define OSLOTS (OUT_D / 2)     // 128; thread owns o = oslot and oslot+128

typedef float v2f __attribute__((ext_vector_type(2)));
typedef float v4f __attribute__((ext_vector_type(4)));

// ws: float4 wlr2[ii2*OUT+o] = {wl(2ii2,o), wr(2ii2,o), wl(2ii2+1,o), wr(2ii2+1,o)}
#define WLR_BYTES (sizeof(float4) * NI2 * OUT_D)   // 512 KB

__global__ __launch_bounds__(256) void fz_prep(
    const float* __restrict__ wb, const float* __restrict__ wa,
    const float* __restrict__ wc, float4* __restrict__ wlr2) {
    int t = blockIdx.x * 256 + threadIdx.x;        // 0 .. NI2*OUT-1
    int ii2 = t >> 8;
    int o   = t & (OUT_D - 1);
    int i0  = (2 * ii2) * OUT_D + o;
    int i1  = i0 + OUT_D;
    float4 w;
    w.x = wb[i0] - fmaxf(wa[i0], 0.0f);
    w.y = wb[i0] + fmaxf(wc[i0], 0.0f);
    w.z = wb[i1] - fmaxf(wa[i1], 0.0f);
    w.w = wb[i1] + fmaxf(wc[i1], 0.0f);
    wlr2[t] = w;
}

__device__ __forceinline__ void fz_cell(v2f p, float wl, float wr, v2f& acc) {
    // invariants: p.y>=p.x (hr>=hl) and wr>0
    //   min(p1..p4) = min3(a*wl, b*wl, a*wr); max(p1..p4) = max3(a*wl, b*wl, b*wr)
    v2f l = p * wl;                                // {a*wl, b*wl}
    v2f r = p * wr;                                // {a*wr, b*wr}
    v2f mm;
    mm.x = fminf(fminf(l.x, l.y), r.x);            // v_min3_f32
    mm.y = fmaxf(fmaxf(l.x, l.y), r.y);            // v_max3_f32
    acc += mm;
}

template <bool PREP>
__global__ __launch_bounds__(1024) void fz_fused(
    const float* __restrict__ hl, const float* __restrict__ hr,
    const float* __restrict__ wb, const float* __restrict__ wa,
    const float* __restrict__ wc, const float4* __restrict__ wlr2,
    const float* __restrict__ bb, const float* __restrict__ ba,
    const float* __restrict__ bc, float* __restrict__ out) {
    __shared__ __align__(16) v2f ab[BN][IN_D];            // 8 KB {hl,hr}
    __shared__ __align__(16) v2f pl[NG][BN][2][OSLOTS];   // 64 KB partials

    const int tid   = threadIdx.x;
    const int oslot = tid & (OSLOTS - 1);          // o0 = oslot, o1 = oslot+128
    const int g     = tid >> 7;                    // K-group 0..7
    const int n0    = blockIdx.x * BN;

    // stage BN rows of {hl,hr}: one (row, ii) per thread, coalesced
    {
        int row = tid >> 8;
        int ii  = tid & (IN_D - 1);
        v2f v; v.x = hl[(n0 + row) * IN_D + ii];
        v.y = hr[(n0 + row) * IN_D + ii];
        ab[row][ii] = v;
    }
    __syncthreads();

    v2f acc[BN][2];
#pragma unroll
    for (int t = 0; t < BN; ++t) {
        acc[t][0] = (v2f)(0.0f);
        acc[t][1] = (v2f)(0.0f);
    }

    const int j0 = g * JPG;
    const float4* wp0 = wlr2 + (size_t)j0 * OUT_D + oslot;   // o0 stream
    const float4* wp1 = wp0 + OSLOTS;                        // o1 stream

    // ---- raw-W loader (fallback when no ws) ----
    auto raw_w = [&](int j, float4& w0, float4& w1) {
        int base = (j0 + j) * 2 * OUT_D + oslot;
        float b00 = wb[base],          a00 = wa[base],          c00 = wc[base];
        float b01 = wb[base + OSLOTS], a01 = wa[base + OSLOTS], c01 = wc[base + OSLOTS];
        float b10 = wb[base + OUT_D],  a10 = wa[base + OUT_D],  c10 = wc[base + OUT_D];
        float b11 = wb[base + OUT_D + OSLOTS], a11 = wa[base + OUT_D + OSLOTS],
              c11 = wc[base + OUT_D + OSLOTS];
        w0.x = b00 - fmaxf(a00, 0.0f); w0.y = b00 + fmaxf(c00, 0.0f);
        w0.z = b10 - fmaxf(a10, 0.0f); w0.w = b10 + fmaxf(c10, 0.0f);
        w1.x = b01 - fmaxf(a01, 0.0f); w1.y = b01 + fmaxf(c01, 0.0f);
        w1.z = b11 - fmaxf(a11, 0.0f); w1.w = b11 + fmaxf(c11, 0.0f);
    };

    // ---- depth-2 register double-buffer on the W stream ----
    float4 wb0[2], wb1[2];
    if (PREP) {
        wb0[0] = wp0[0];                 wb1[0] = wp1[0];
        wb0[1] = wp0[(size_t)1 * OUT_D]; wb1[1] = wp1[(size_t)1 * OUT_D];
    } else {
        raw_w(0, wb0[0], wb1[0]);
        raw_w(1, wb0[1], wb1[1]);
    }

    // depth-1 prefetch of the h LDS reads
    v4f a4c[BN], a4n[BN];
#pragma unroll
    for (int t = 0; t < BN; ++t)
        a4c[t] = *reinterpret_cast<const v4f*>(&ab[t][j0 * 2]);

#pragma unroll
    for (int j = 0; j < JPG; ++j) {
        float4 w0 = wb0[j & 1], w1 = wb1[j & 1];
        if (j + 2 < JPG) {               // static under full unroll
            if (PREP) {
                wb0[j & 1] = wp0[(size_t)(j + 2) * OUT_D];
                wb1[j & 1] = wp1[(size_t)(j + 2) * OUT_D];
            } else {
                raw_w(j + 2, wb0[j & 1], wb1[j & 1]);
            }
        }
        if (j + 1 < JPG) {
            const int iin = (j0 + j + 1) * 2;
#pragma unroll
            for (int t = 0; t < BN; ++t)
                a4n[t] = *reinterpret_cast<const v4f*>(&ab[t][iin]);
        }
#pragma unroll
        for (int t = 0; t < BN; ++t) {
            v4f a4 = a4c[t];
            v2f p0; p0.x = a4.x; p0.y = a4.y;      // {a,b} at i_a
            v2f p1; p1.x = a4.z; p1.y = a4.w;      // {a,b} at i_b
            fz_cell(p0, w0.x, w0.y, acc[t][0]);    // o0, i_a
            fz_cell(p1, w0.z, w0.w, acc[t][0]);    // o0, i_b
            fz_cell(p0, w1.x, w1.y, acc[t][1]);    // o1, i_a
            fz_cell(p1, w1.z, w1.w, acc[t][1]);    // o1, i_b
        }
#pragma unroll
        for (int t = 0; t < BN; ++t) a4c[t] = a4n[t];
    }

    // partials (8B stride: 2-way aliasing = free)
#pragma unroll
    for (int t = 0; t < BN; ++t) {
        pl[g][t][0][oslot] = acc[t][0];
        pl[g][t][1][oslot] = acc[t][1];
    }
    __syncthreads();

    // groups 0..3 each combine one row
    if (g < BN) {
        const int row = g;
        const int o0 = oslot, o1 = oslot + OSLOTS;
        v2f s0 = (v2f)(0.0f), s1 = (v2f)(0.0f);
#pragma unroll
        for (int gg = 0; gg < NG; ++gg) {
            s0 += pl[gg][row][0][oslot];
            s1 += pl[gg][row][1][oslot];
        }
        float bl0 = bb[o0] - fmaxf(ba[o0], 0.0f);
        float br0 = bb[o0] + fmaxf(bc[o0], 0.0f);
        float bl1 = bb[o1] - fmaxf(ba[o1], 0.0f);
        float br1 = bb[o1] + fmaxf(bc[o1], 0.0f);
        size_t rl = (size_t)(n0 + row) * OUT_D;
        size_t rr = (size_t)NN * OUT_D + rl;
        out[rl + o0] = s0.x + bl0;
        out[rr + o0] = s0.y + br0;
        out[rl + o1] = s1.x + bl1;
        out[rr + o1] = s1.y + br1;
    }
}

extern "C" void kernel_launch(void* const* d_in, const int* in_sizes, int n_in,
                              void* d_out, int out_size, void* d_ws, size_t ws_size,
                              hipStream_t stream) {
    const float* hl = (const float*)d_in[0];
    const float* hr = (const float*)d_in[1];
    const float* wb = (const float*)d_in[2];
    const float* wa = (const float*)d_in[3];
    const float* wc = (const float*)d_in[4];
    const float* bb = (const float*)d_in[5];
    const float* ba = (const float*)d_in[6];
    const float* bc = (const float*)d_in[7];
    float* out = (float*)d_out;

    dim3 grid(NN / BN);

    if (ws_size >= WLR_BYTES) {
        float4* wlr2 = (float4*)d_ws;
        fz_prep<<<(NI2 * OUT_D) / 256, 256, 0, stream>>>(wb, wa, wc, wlr2);
        fz_fused<true><<<grid, 1024, 0, stream>>>(hl, hr, wb, wa, wc, wlr2,
                                                  bb, ba, bc, out);
    } else {
        fz_fused<false><<<grid, 1024, 0, stream>>>(hl, hr, wb, wa, wc, nullptr,
                                                   bb, ba, bc, out);
    }
}